// Round 1
// baseline (558.360 us; speedup 1.0000x reference)
//
#include <hip/hip_runtime.h>
#include <hip/hip_bf16.h>

#define N_NODES 50000
#define N_EDGES 800000
#define DFEAT   128

// ---------------- CSR build ----------------

__global__ void hist_kernel(const int* __restrict__ dst, int* __restrict__ cnt, int E) {
    int i = blockIdx.x * blockDim.x + threadIdx.x;
    if (i < E) atomicAdd(&cnt[dst[i]], 1);
}

__global__ __launch_bounds__(1024) void scan_kernel(const int* __restrict__ cnt,
                                                    int* __restrict__ rowptr,
                                                    int* __restrict__ cursor, int n) {
    __shared__ int wsum[16];
    __shared__ int woff[17];
    __shared__ int run_s;
    const int tid = threadIdx.x, lane = tid & 63, wid = tid >> 6;
    if (tid == 0) run_s = 0;
    __syncthreads();
    for (int base = 0; base < n; base += 1024) {
        int i = base + tid;
        int v = (i < n) ? cnt[i] : 0;
        // wave-level inclusive scan
        int s = v;
        #pragma unroll
        for (int off = 1; off < 64; off <<= 1) {
            int t = __shfl_up(s, off, 64);
            if (lane >= off) s += t;
        }
        if (lane == 63) wsum[wid] = s;
        __syncthreads();
        if (tid == 0) {
            int acc = 0;
            #pragma unroll
            for (int w = 0; w < 16; ++w) { woff[w] = acc; acc += wsum[w]; }
            woff[16] = acc;
        }
        __syncthreads();
        int run = run_s;
        int excl = run + woff[wid] + (s - v);
        if (i < n) { rowptr[i] = excl; cursor[i] = excl; }
        __syncthreads();               // everyone has read run_s
        if (tid == 0) run_s = run + woff[16];
        __syncthreads();
    }
    if (tid == 0) rowptr[n] = run_s;
}

__global__ void scatter_kernel(const int* __restrict__ src, const int* __restrict__ dst,
                               const float* __restrict__ ew,
                               int* __restrict__ cursor, int2* __restrict__ edges, int E) {
    int i = blockIdx.x * blockDim.x + threadIdx.x;
    if (i < E) {
        int d = dst[i];
        int pos = atomicAdd(&cursor[d], 1);
        edges[pos] = make_int2(src[i], __float_as_int(ew[i]));
    }
}

// ---------------- weight prep: Bcat[k][j]; rows 0..127 = w_rel^T, 128..255 = w_root^T ----

__global__ void prep_B(const float* __restrict__ wrel, const float* __restrict__ wroot,
                       float* __restrict__ B) {
    int idx = blockIdx.x * blockDim.x + threadIdx.x;   // 0 .. 16383
    if (idx >= 128 * 128) return;
    int k = idx >> 7, j = idx & 127;
    B[k * 128 + j]         = wrel[j * 128 + k];
    B[(k + 128) * 128 + j] = wroot[j * 128 + k];
}

// ---------------- aggregation: one wave per node, 2 floats/lane ----------------

__global__ __launch_bounds__(256) void aggregate_kernel(const float* __restrict__ xin,
                                                        const int* __restrict__ rowptr,
                                                        const int2* __restrict__ edges,
                                                        float* __restrict__ agg, int N) {
    int node = blockIdx.x * 4 + (threadIdx.x >> 6);
    int lane = threadIdx.x & 63;
    if (node >= N) return;
    int beg = rowptr[node];
    int end = rowptr[node + 1];
    float2 acc = make_float2(0.f, 0.f);
    for (int e = beg; e < end; ++e) {
        int2 sw = edges[e];
        float w = __int_as_float(sw.y);
        const float2* row = (const float2*)(xin + (size_t)sw.x * DFEAT);
        float2 v = row[lane];
        acc.x = fmaf(w, v.x, acc.x);
        acc.y = fmaf(w, v.y, acc.y);
    }
    ((float2*)(agg + (size_t)node * DFEAT))[lane] = acc;
}

// ---------------- fused GEMM: out[M,128] = [agg|x][M,256] @ Bcat[256,128] + b ----------

#define BM 128
#define BN 128
#define KB 16

template<int RELU>
__global__ __launch_bounds__(256) void gemm_fused(const float* __restrict__ Aagg,
                                                  const float* __restrict__ Ax,
                                                  const float* __restrict__ Bcat,
                                                  const float* __restrict__ bias,
                                                  float* __restrict__ out, int M) {
    __shared__ float As[KB][BM + 4];
    __shared__ float Bs[KB][BN + 4];
    const int tid = threadIdx.x;
    const int tx = tid & 15;        // col group: 8 cols each
    const int ty = tid >> 4;        // row group: 8 rows each
    const int gm0 = blockIdx.x * BM;

    float acc[8][8];
    #pragma unroll
    for (int r = 0; r < 8; ++r)
        #pragma unroll
        for (int c = 0; c < 8; ++c) acc[r][c] = 0.f;

    for (int k0 = 0; k0 < 256; k0 += KB) {
        const float* Asrc = (k0 < 128) ? Aagg : Ax;
        const int kk = (k0 < 128) ? k0 : (k0 - 128);
        // stage A tile (transposed): As[k][m]
        {
            int m = tid >> 1;            // 0..127
            int half = tid & 1;          // 0/1 -> k offset 0/8
            int row = gm0 + m; if (row >= M) row = M - 1;
            const float4* p = (const float4*)(Asrc + (size_t)row * DFEAT + kk + half * 8);
            float4 q0 = p[0], q1 = p[1];
            int kb = half * 8;
            As[kb + 0][m] = q0.x; As[kb + 1][m] = q0.y; As[kb + 2][m] = q0.z; As[kb + 3][m] = q0.w;
            As[kb + 4][m] = q1.x; As[kb + 5][m] = q1.y; As[kb + 6][m] = q1.z; As[kb + 7][m] = q1.w;
        }
        // stage B tile: Bs[k][j]
        {
            int k = tid >> 4;            // 0..15
            int j = (tid & 15) * 8;      // 0..120
            const float4* p = (const float4*)(Bcat + (size_t)(k0 + k) * 128 + j);
            *(float4*)&Bs[k][j]     = p[0];
            *(float4*)&Bs[k][j + 4] = p[1];
        }
        __syncthreads();
        #pragma unroll
        for (int k = 0; k < KB; ++k) {
            float a[8], b[8];
            *(float4*)&a[0] = *(const float4*)&As[k][ty * 8];
            *(float4*)&a[4] = *(const float4*)&As[k][ty * 8 + 4];
            *(float4*)&b[0] = *(const float4*)&Bs[k][tx * 8];
            *(float4*)&b[4] = *(const float4*)&Bs[k][tx * 8 + 4];
            #pragma unroll
            for (int r = 0; r < 8; ++r)
                #pragma unroll
                for (int c = 0; c < 8; ++c)
                    acc[r][c] = fmaf(a[r], b[c], acc[r][c]);
        }
        __syncthreads();
    }
    // epilogue: bias (+ relu), vectorized store
    #pragma unroll
    for (int r = 0; r < 8; ++r) {
        int row = gm0 + ty * 8 + r;
        if (row < M) {
            #pragma unroll
            for (int c = 0; c < 8; c += 4) {
                int col = tx * 8 + c;
                float4 v;
                v.x = acc[r][c + 0] + bias[col + 0];
                v.y = acc[r][c + 1] + bias[col + 1];
                v.z = acc[r][c + 2] + bias[col + 2];
                v.w = acc[r][c + 3] + bias[col + 3];
                if (RELU) {
                    v.x = fmaxf(v.x, 0.f); v.y = fmaxf(v.y, 0.f);
                    v.z = fmaxf(v.z, 0.f); v.w = fmaxf(v.w, 0.f);
                }
                *(float4*)(out + (size_t)row * 128 + col) = v;
            }
        }
    }
}

// ---------------- launch ----------------

extern "C" void kernel_launch(void* const* d_in, const int* in_sizes, int n_in,
                              void* d_out, int out_size, void* d_ws, size_t ws_size,
                              hipStream_t stream) {
    const float* x     = (const float*)d_in[0];
    const int*   eidx  = (const int*)d_in[1];
    const float* ew    = (const float*)d_in[2];
    const float* w1r   = (const float*)d_in[3];
    const float* w1t   = (const float*)d_in[4];
    const float* b1    = (const float*)d_in[5];
    const float* w2r   = (const float*)d_in[6];
    const float* w2t   = (const float*)d_in[7];
    const float* b2    = (const float*)d_in[8];
    const float* w3r   = (const float*)d_in[9];
    const float* w3t   = (const float*)d_in[10];
    const float* b3    = (const float*)d_in[11];
    float* out = (float*)d_out;

    const int N = in_sizes[0] / DFEAT;       // 50000
    const int E = in_sizes[2];               // 800000

    // workspace bump allocator (256B aligned)
    char* ws = (char*)d_ws;
    size_t off = 0;
    auto alloc = [&](size_t bytes) -> void* {
        off = (off + 255) & ~(size_t)255;
        void* p = ws + off;
        off += bytes;
        return p;
    };
    int*   cnt    = (int*)alloc((size_t)N * 4);
    int*   rowptr = (int*)alloc((size_t)(N + 1) * 4);
    int*   cursor = (int*)alloc((size_t)N * 4);
    int2*  edges  = (int2*)alloc((size_t)E * 8);
    float* B1     = (float*)alloc(256 * 128 * 4);
    float* B2     = (float*)alloc(256 * 128 * 4);
    float* B3     = (float*)alloc(256 * 128 * 4);
    float* agg    = (float*)alloc((size_t)N * DFEAT * 4);
    float* h1     = (float*)alloc((size_t)N * DFEAT * 4);
    float* h2     = (float*)alloc((size_t)N * DFEAT * 4);
    (void)ws_size;

    const int* src = eidx;
    const int* dst = eidx + E;

    // CSR by dst
    hipMemsetAsync(cnt, 0, (size_t)N * 4, stream);
    hist_kernel<<<(E + 255) / 256, 256, 0, stream>>>(dst, cnt, E);
    scan_kernel<<<1, 1024, 0, stream>>>(cnt, rowptr, cursor, N);
    scatter_kernel<<<(E + 255) / 256, 256, 0, stream>>>(src, dst, ew, cursor, edges, E);

    // weight prep
    prep_B<<<64, 256, 0, stream>>>(w1r, w1t, B1);
    prep_B<<<64, 256, 0, stream>>>(w2r, w2t, B2);
    prep_B<<<64, 256, 0, stream>>>(w3r, w3t, B3);

    const int aggGrid  = (N + 3) / 4;
    const int gemmGrid = (N + BM - 1) / BM;

    // layer 1
    aggregate_kernel<<<aggGrid, 256, 0, stream>>>(x, rowptr, edges, agg, N);
    gemm_fused<1><<<gemmGrid, 256, 0, stream>>>(agg, x, B1, b1, h1, N);
    // layer 2
    aggregate_kernel<<<aggGrid, 256, 0, stream>>>(h1, rowptr, edges, agg, N);
    gemm_fused<1><<<gemmGrid, 256, 0, stream>>>(agg, h1, B2, b2, h2, N);
    // layer 3
    aggregate_kernel<<<aggGrid, 256, 0, stream>>>(h2, rowptr, edges, agg, N);
    gemm_fused<0><<<gemmGrid, 256, 0, stream>>>(agg, h2, B3, b3, out, N);
}

// Round 2
// 280.976 us; speedup vs baseline: 1.9872x; 1.9872x over previous
//
#include <hip/hip_runtime.h>
#include <hip/hip_bf16.h>

#define N_NODES 50000
#define N_EDGES 800000
#define DFEAT   128

typedef __attribute__((ext_vector_type(8))) short bf16x8;
typedef __attribute__((ext_vector_type(4))) float f32x4;
typedef unsigned int uint;

// ---------------- CSR build ----------------

__global__ void hist_kernel(const int* __restrict__ dst, int* __restrict__ cnt, int E) {
    int i = blockIdx.x * blockDim.x + threadIdx.x;
    if (i < E) atomicAdd(&cnt[dst[i]], 1);
}

__global__ __launch_bounds__(1024) void chunk_reduce(const int* __restrict__ cnt,
                                                     int* __restrict__ csum, int n) {
    __shared__ int ws[16];
    int tid = threadIdx.x, lane = tid & 63, wid = tid >> 6;
    int i = blockIdx.x * 1024 + tid;
    int v = (i < n) ? cnt[i] : 0;
    #pragma unroll
    for (int m = 1; m < 64; m <<= 1) v += __shfl_xor(v, m, 64);
    if (lane == 0) ws[wid] = v;
    __syncthreads();
    if (tid == 0) {
        int s = 0;
        #pragma unroll
        for (int w = 0; w < 16; ++w) s += ws[w];
        csum[blockIdx.x] = s;
    }
}

__global__ void chunk_scan(const int* __restrict__ csum, int* __restrict__ coff,
                           int* __restrict__ rowptr, int nc, int n) {
    int lane = threadIdx.x;   // 64 threads, nc <= 64
    int v = (lane < nc) ? csum[lane] : 0;
    int s = v;
    #pragma unroll
    for (int off = 1; off < 64; off <<= 1) {
        int t = __shfl_up(s, off, 64);
        if (lane >= off) s += t;
    }
    if (lane < nc) coff[lane] = s - v;     // exclusive chunk offset
    if (lane == 63) rowptr[n] = s;         // grand total
}

__global__ __launch_bounds__(1024) void chunk_prefix(const int* __restrict__ cnt,
                                                     const int* __restrict__ coff,
                                                     int* __restrict__ rowptr,
                                                     int* __restrict__ cursor, int n) {
    __shared__ int wsum[16], woff[16];
    int tid = threadIdx.x, lane = tid & 63, wid = tid >> 6;
    int i = blockIdx.x * 1024 + tid;
    int v = (i < n) ? cnt[i] : 0;
    int s = v;
    #pragma unroll
    for (int off = 1; off < 64; off <<= 1) {
        int t = __shfl_up(s, off, 64);
        if (lane >= off) s += t;
    }
    if (lane == 63) wsum[wid] = s;
    __syncthreads();
    if (tid == 0) {
        int a = 0;
        #pragma unroll
        for (int w = 0; w < 16; ++w) { woff[w] = a; a += wsum[w]; }
    }
    __syncthreads();
    int excl = coff[blockIdx.x] + woff[wid] + (s - v);
    if (i < n) { rowptr[i] = excl; cursor[i] = excl; }
}

__global__ void scatter_kernel(const int* __restrict__ src, const int* __restrict__ dst,
                               const float* __restrict__ ew,
                               int* __restrict__ cursor, int2* __restrict__ edges, int E) {
    int i = blockIdx.x * blockDim.x + threadIdx.x;
    if (i < E) {
        int d = dst[i];
        int pos = atomicAdd(&cursor[d], 1);
        edges[pos] = make_int2(src[i], __float_as_int(ew[i]));
    }
}

// ---------------- f32 -> bf16 conversion (2 floats / thread) ----------------

__device__ __forceinline__ uint pack_bf16x2(float a, float b) {
    __hip_bfloat16 ba = __float2bfloat16(a);
    __hip_bfloat16 bb = __float2bfloat16(b);
    unsigned short ua = *(unsigned short*)&ba;
    unsigned short ub = *(unsigned short*)&bb;
    return (uint)ua | ((uint)ub << 16);
}

__global__ void cvt_kernel(const float* __restrict__ in, uint* __restrict__ out, int n2) {
    int i = blockIdx.x * 256 + threadIdx.x;
    if (i < n2) {
        float2 v = ((const float2*)in)[i];
        out[i] = pack_bf16x2(v.x, v.y);
    }
}

// ------------- weight pack: frag-ordered bf16 for mfma_f32_16x16x32_bf16 -------------
// Bcat[k][n]: k<128 -> wrel[n][k] ; k>=128 -> wroot[n][k-128]
// Bp[((kstep*8 + nfrag)*64 + lane)*8 + j] = Bcat[kstep*32 + (lane>>4)*8 + j][nfrag*16 + (lane&15)]

__global__ void prep_Bpack(const float* __restrict__ wrel, const float* __restrict__ wroot,
                           __hip_bfloat16* __restrict__ Bp) {
    int idx = blockIdx.x * 256 + threadIdx.x;   // 0..32767
    if (idx >= 32768) return;
    int j     = idx & 7;
    int lane  = (idx >> 3) & 63;
    int nfrag = (idx >> 9) & 7;
    int kstep = idx >> 12;
    int k = kstep * 32 + (lane >> 4) * 8 + j;
    int n = nfrag * 16 + (lane & 15);
    float v = (k < 128) ? wrel[n * 128 + k] : wroot[n * 128 + (k - 128)];
    Bp[idx] = __float2bfloat16(v);
}

// ---------------- aggregation: one wave per node, bf16 gather, f32 accum ----------------
// f: [N][64] uint (2 bf16 each).  Acat: [N][128] uint = [N][256] bf16:
//   cols 0..127 = agg, cols 128..255 = root copy

__global__ __launch_bounds__(256) void aggregate_bf16(const uint* __restrict__ f,
                                                      const int* __restrict__ rowptr,
                                                      const int2* __restrict__ edges,
                                                      uint* __restrict__ Acat, int N) {
    int node = blockIdx.x * 4 + (threadIdx.x >> 6);
    int lane = threadIdx.x & 63;
    if (node >= N) return;
    int beg = rowptr[node];
    int end = rowptr[node + 1];
    float ax0 = 0.f, ay0 = 0.f, ax1 = 0.f, ay1 = 0.f;
    float ax2 = 0.f, ay2 = 0.f, ax3 = 0.f, ay3 = 0.f;
    int e = beg;
    for (; e + 4 <= end; e += 4) {
        int2 e0 = edges[e + 0], e1 = edges[e + 1], e2 = edges[e + 2], e3 = edges[e + 3];
        uint v0 = f[(size_t)e0.x * 64 + lane];
        uint v1 = f[(size_t)e1.x * 64 + lane];
        uint v2 = f[(size_t)e2.x * 64 + lane];
        uint v3 = f[(size_t)e3.x * 64 + lane];
        float w0 = __int_as_float(e0.y), w1 = __int_as_float(e1.y);
        float w2 = __int_as_float(e2.y), w3 = __int_as_float(e3.y);
        ax0 = fmaf(w0, __uint_as_float(v0 << 16), ax0);
        ay0 = fmaf(w0, __uint_as_float(v0 & 0xffff0000u), ay0);
        ax1 = fmaf(w1, __uint_as_float(v1 << 16), ax1);
        ay1 = fmaf(w1, __uint_as_float(v1 & 0xffff0000u), ay1);
        ax2 = fmaf(w2, __uint_as_float(v2 << 16), ax2);
        ay2 = fmaf(w2, __uint_as_float(v2 & 0xffff0000u), ay2);
        ax3 = fmaf(w3, __uint_as_float(v3 << 16), ax3);
        ay3 = fmaf(w3, __uint_as_float(v3 & 0xffff0000u), ay3);
    }
    for (; e < end; ++e) {
        int2 ee = edges[e];
        uint v = f[(size_t)ee.x * 64 + lane];
        float w = __int_as_float(ee.y);
        ax0 = fmaf(w, __uint_as_float(v << 16), ax0);
        ay0 = fmaf(w, __uint_as_float(v & 0xffff0000u), ay0);
    }
    float ax = (ax0 + ax1) + (ax2 + ax3);
    float ay = (ay0 + ay1) + (ay2 + ay3);
    uint* arow = Acat + (size_t)node * 128;
    arow[lane]      = pack_bf16x2(ax, ay);          // agg half
    arow[64 + lane] = f[(size_t)node * 64 + lane];  // root half
}

// ---------------- MFMA GEMM: C[M,128] = Acat[M,256] @ Bcat[256,128] + bias ----------------
// 128x128 block tile, 4 waves (2x2), each wave 64x64 = 4x4 frags of 16x16, K-loop 8 x 32.
// A frag: lane reads A[m0+mi*16+(lane&15)][ks*32+(lane>>4)*8 .. +8]  (16B)
// B frag: packed, Bp[(ks*8 + nfragGlobal)*64 + lane]                 (16B coalesced)

template<int RELU, int OUTF32>
__global__ __launch_bounds__(256) void gemm_mfma(const __hip_bfloat16* __restrict__ A,
                                                 const bf16x8* __restrict__ Bp,
                                                 const float* __restrict__ bias,
                                                 float* __restrict__ outf,
                                                 __hip_bfloat16* __restrict__ outb, int M) {
    const int tid  = threadIdx.x;
    const int lane = tid & 63, wid = tid >> 6;
    const int wr = wid >> 1, wc = wid & 1;
    const int m0 = blockIdx.x * 128 + wr * 64;
    const int n0 = wc * 64;

    f32x4 acc[4][4];
    #pragma unroll
    for (int mi = 0; mi < 4; ++mi)
        #pragma unroll
        for (int ni = 0; ni < 4; ++ni) acc[mi][ni] = (f32x4){0.f, 0.f, 0.f, 0.f};

    const short* As = (const short*)A;
    const int lrow = lane & 15;
    const int lk   = (lane >> 4) * 8;
    int rowidx[4];
    #pragma unroll
    for (int mi = 0; mi < 4; ++mi) {
        int r = m0 + mi * 16 + lrow;
        rowidx[mi] = (r < M) ? r : (M - 1);
    }

    #pragma unroll
    for (int ks = 0; ks < 8; ++ks) {
        bf16x8 a[4], b[4];
        #pragma unroll
        for (int mi = 0; mi < 4; ++mi)
            a[mi] = *(const bf16x8*)(As + (size_t)rowidx[mi] * 256 + ks * 32 + lk);
        #pragma unroll
        for (int ni = 0; ni < 4; ++ni)
            b[ni] = Bp[(ks * 8 + (wc * 4 + ni)) * 64 + lane];
        #pragma unroll
        for (int mi = 0; mi < 4; ++mi)
            #pragma unroll
            for (int ni = 0; ni < 4; ++ni)
                acc[mi][ni] = __builtin_amdgcn_mfma_f32_16x16x32_bf16(a[mi], b[ni], acc[mi][ni], 0, 0, 0);
    }

    // epilogue: C row = m0 + mi*16 + (lane>>4)*4 + r ; col = n0 + ni*16 + (lane&15)
    const int crow = (lane >> 4) * 4;
    const int ccol = lane & 15;
    #pragma unroll
    for (int mi = 0; mi < 4; ++mi) {
        #pragma unroll
        for (int ni = 0; ni < 4; ++ni) {
            int col = n0 + ni * 16 + ccol;
            float bv = bias[col];
            #pragma unroll
            for (int r = 0; r < 4; ++r) {
                int row = m0 + mi * 16 + crow + r;
                if (row < M) {
                    float v = acc[mi][ni][r] + bv;
                    if (RELU) v = fmaxf(v, 0.f);
                    if (OUTF32) {
                        outf[(size_t)row * 128 + col] = v;
                    } else {
                        __hip_bfloat16 h = __float2bfloat16(v);
                        outb[(size_t)row * 128 + col] = h;
                    }
                }
            }
        }
    }
}

// ---------------- launch ----------------

extern "C" void kernel_launch(void* const* d_in, const int* in_sizes, int n_in,
                              void* d_out, int out_size, void* d_ws, size_t ws_size,
                              hipStream_t stream) {
    const float* x   = (const float*)d_in[0];
    const int*  eidx = (const int*)d_in[1];
    const float* ew  = (const float*)d_in[2];
    const float* w1r = (const float*)d_in[3];
    const float* w1t = (const float*)d_in[4];
    const float* b1  = (const float*)d_in[5];
    const float* w2r = (const float*)d_in[6];
    const float* w2t = (const float*)d_in[7];
    const float* b2  = (const float*)d_in[8];
    const float* w3r = (const float*)d_in[9];
    const float* w3t = (const float*)d_in[10];
    const float* b3  = (const float*)d_in[11];
    float* out = (float*)d_out;

    const int N = in_sizes[0] / DFEAT;   // 50000
    const int E = in_sizes[2];           // 800000
    const int NC = (N + 1023) / 1024;    // scan chunks

    char* ws = (char*)d_ws;
    size_t off = 0;
    auto alloc = [&](size_t bytes) -> void* {
        off = (off + 255) & ~(size_t)255;
        void* p = ws + off;
        off += bytes;
        return p;
    };
    int*  cnt    = (int*)alloc((size_t)N * 4);
    int*  rowptr = (int*)alloc((size_t)(N + 1) * 4);
    int*  cursor = (int*)alloc((size_t)N * 4);
    int*  csum   = (int*)alloc(64 * 4);
    int*  coff   = (int*)alloc(64 * 4);
    int2* edges  = (int2*)alloc((size_t)E * 8);
    __hip_bfloat16* Bp1 = (__hip_bfloat16*)alloc(32768 * 2);
    __hip_bfloat16* Bp2 = (__hip_bfloat16*)alloc(32768 * 2);
    __hip_bfloat16* Bp3 = (__hip_bfloat16*)alloc(32768 * 2);
    uint* xb   = (uint*)alloc((size_t)N * 64 * 4);    // bf16 [N][128]
    uint* Acat = (uint*)alloc((size_t)N * 128 * 4);   // bf16 [N][256]
    uint* h1b  = (uint*)alloc((size_t)N * 64 * 4);
    uint* h2b  = (uint*)alloc((size_t)N * 64 * 4);
    (void)ws_size;

    const int* src = eidx;
    const int* dst = eidx + E;

    // CSR by dst (multi-block scan)
    hipMemsetAsync(cnt, 0, (size_t)N * 4, stream);
    hist_kernel<<<(E + 255) / 256, 256, 0, stream>>>(dst, cnt, E);
    chunk_reduce<<<NC, 1024, 0, stream>>>(cnt, csum, N);
    chunk_scan<<<1, 64, 0, stream>>>(csum, coff, rowptr, NC, N);
    chunk_prefix<<<NC, 1024, 0, stream>>>(cnt, coff, rowptr, cursor, N);
    scatter_kernel<<<(E + 255) / 256, 256, 0, stream>>>(src, dst, ew, cursor, edges, E);

    // feature + weight conversion
    cvt_kernel<<<(N * 64 + 255) / 256, 256, 0, stream>>>(x, xb, N * 64);
    prep_Bpack<<<128, 256, 0, stream>>>(w1r, w1t, Bp1);
    prep_Bpack<<<128, 256, 0, stream>>>(w2r, w2t, Bp2);
    prep_Bpack<<<128, 256, 0, stream>>>(w3r, w3t, Bp3);

    const int aggGrid  = (N + 3) / 4;
    const int gemmGrid = (N + 127) / 128;

    // layer 1
    aggregate_bf16<<<aggGrid, 256, 0, stream>>>(xb, rowptr, edges, Acat, N);
    gemm_mfma<1, 0><<<gemmGrid, 256, 0, stream>>>((const __hip_bfloat16*)Acat, (const bf16x8*)Bp1,
                                                  b1, nullptr, (__hip_bfloat16*)h1b, N);
    // layer 2
    aggregate_bf16<<<aggGrid, 256, 0, stream>>>(h1b, rowptr, edges, Acat, N);
    gemm_mfma<1, 0><<<gemmGrid, 256, 0, stream>>>((const __hip_bfloat16*)Acat, (const bf16x8*)Bp2,
                                                  b2, nullptr, (__hip_bfloat16*)h2b, N);
    // layer 3
    aggregate_bf16<<<aggGrid, 256, 0, stream>>>(h2b, rowptr, edges, Acat, N);
    gemm_mfma<0, 1><<<gemmGrid, 256, 0, stream>>>((const __hip_bfloat16*)Acat, (const bf16x8*)Bp3,
                                                  b3, out, nullptr, N);
}